// Round 10
// baseline (10582.114 us; speedup 1.0000x reference)
//
#include <hip/hip_runtime.h>
#include <stdint.h>

#define Bb 4
#define Hh 4
#define Tt 8
#define Cc 256
#define NP 196
#define Ss 1568                 // Tt*NP
#define SCALE_S 0.0252538136f   // 1/sqrt(1568)

// ============ ALL-FP32 PIPELINE (output buffer is fp32 — proven R9) ============

// ---- K1: emb [B,T,C,N] -> x [B,S,C] (transpose last two dims per (b,t)) ----
__global__ void k_transpose(const float* __restrict__ emb, float* __restrict__ x) {
    __shared__ float tile[32][33];
    int bt = blockIdx.z;                       // b*T + t
    int c0 = blockIdx.y * 32, n0 = blockIdx.x * 32;
    const float* src = emb + (size_t)bt * Cc * NP;
#pragma unroll
    for (int rr = 0; rr < 32; rr += 8) {
        int c = c0 + threadIdx.y + rr;
        int n = n0 + threadIdx.x;
        float v = 0.f;
        if (n < NP) v = src[(size_t)c * NP + n];
        tile[threadIdx.y + rr][threadIdx.x] = v;
    }
    __syncthreads();
    int b = bt / Tt, t = bt % Tt;
    float* dst = x + ((size_t)b * Ss + (size_t)t * NP) * Cc;
#pragma unroll
    for (int rr = 0; rr < 32; rr += 8) {
        int n = n0 + threadIdx.y + rr;
        int c = c0 + threadIdx.x;
        if (n < NP) dst[(size_t)n * Cc + c] = tile[threadIdx.x][threadIdx.y + rr];
    }
}

// ---- K2 per-bh: Qb/Kbb/Vb [S,C]. grid=(S,3); out[s,d] = sum_c x[b,s,c]*W[h,d,c] ----
__global__ __launch_bounds__(256) void k_qkv_small(const float* __restrict__ x,
                                                   const float* __restrict__ Wq,
                                                   const float* __restrict__ Wk,
                                                   const float* __restrict__ Wv,
                                                   float* __restrict__ Qb, float* __restrict__ Kbb,
                                                   float* __restrict__ Vb, int bh) {
    __shared__ float xs[Cc];
    int s = blockIdx.x, which = blockIdx.y;
    int b = bh >> 2, h = bh & 3;
    int d = threadIdx.x;
    xs[d] = x[((size_t)b * Ss + s) * Cc + d];
    __syncthreads();
    const float* W = (which == 0 ? Wq : (which == 1 ? Wk : Wv)) + ((size_t)h * Cc + d) * Cc;
    float acc = 0.f;
#pragma unroll 8
    for (int c = 0; c < Cc; ++c)
        acc += xs[c] * W[c];
    float* out = (which == 0 ? Qb : (which == 1 ? Kbb : Vb));
    out[(size_t)s * Cc + d] = acc;
}

// ---- K3 per-bh: Sc[s,t] = (Qb[s,:]·Kbb[t,:])*SCALE_S + fp32 stats atomics ----
__global__ __launch_bounds__(256) void k_scores_small(const float* __restrict__ Qb,
                                                      const float* __restrict__ Kbb,
                                                      float* __restrict__ Sc,
                                                      float* __restrict__ stats, int bh) {
    __shared__ float qs[Cc];
    __shared__ float sred[8];
    int s = blockIdx.x;
    int tid = threadIdx.x, lane = tid & 63, wave = tid >> 6;
    qs[tid] = Qb[(size_t)s * Cc + tid];
    __syncthreads();
    float* srow = Sc + (size_t)s * Ss;
    float lsum = 0.f, lsq = 0.f;
    for (int rep = 0; rep < 7; ++rep) {
        int t = tid + rep * 256;
        if (t < Ss) {
            const float* krow = Kbb + (size_t)t * Cc;
            float acc = 0.f;
#pragma unroll 8
            for (int c = 0; c < Cc; ++c)
                acc += qs[c] * krow[c];
            float v = acc * SCALE_S;
            srow[t] = v;
            lsum += v; lsq += v * v;
        }
    }
#pragma unroll
    for (int mk = 1; mk <= 32; mk <<= 1) { lsum += __shfl_xor(lsum, mk); lsq += __shfl_xor(lsq, mk); }
    if (lane == 0) { sred[wave] = lsum; sred[4 + wave] = lsq; }
    __syncthreads();
    if (tid == 0) atomicAdd(&stats[bh * 4 + 0], sred[0] + sred[1] + sred[2] + sred[3]);
    if (tid == 1) atomicAdd(&stats[bh * 4 + 1], sred[4] + sred[5] + sred[6] + sred[7]);
}

// ---- K4 per-bh: finalize mean / inv-std ----
__global__ void k_stats1(float* __restrict__ stats, int bh) {
    if (threadIdx.x == 0) {
        float inv  = 1.f / ((float)Ss * (float)Ss);
        float mean = stats[bh * 4] * inv;
        float var  = stats[bh * 4 + 1] * inv - mean * mean;
        var = fmaxf(var, 0.f);
        stats[bh * 4 + 2] = mean;
        stats[bh * 4 + 3] = rsqrtf(var + 1e-5f);
    }
}

// ---- K5 per-bh: ctxm[b,s,:] += 0.25 * softmax_row((Sc[s,:]-mean)*istd) @ Vb ----
__global__ __launch_bounds__(256) void k_pv_small(const float* __restrict__ Sc,
                                                  const float* __restrict__ Vb,
                                                  const float* __restrict__ stats,
                                                  float* __restrict__ ctxm, int bh) {
    __shared__ float ps[Ss];
    __shared__ float red[4];
    int s = blockIdx.x;
    int tid = threadIdx.x, lane = tid & 63, wave = tid >> 6;
    float mean = stats[bh * 4 + 2], istd = stats[bh * 4 + 3];
    const float* srow = Sc + (size_t)s * Ss;
    float part = 0.f;
    for (int rep = 0; rep < 7; ++rep) {
        int t = tid + rep * 256;
        if (t < Ss) {
            float e = __expf((srow[t] - mean) * istd);
            ps[t] = e; part += e;
        }
    }
#pragma unroll
    for (int mk = 1; mk <= 32; mk <<= 1) part += __shfl_xor(part, mk);
    if (lane == 0) red[wave] = part;
    __syncthreads();
    float invrs = 1.f / (red[0] + red[1] + red[2] + red[3]);
    float acc = 0.f;
    for (int t = 0; t < Ss; ++t)
        acc += ps[t] * Vb[(size_t)t * Cc + tid];
    int b = bh >> 2;
    ctxm[((size_t)b * Ss + s) * Cc + tid] += 0.25f * acc * invrs;   // sequential per b: no race
}

// ---- K6: out[b,s,d] = sum_c ctxm[b,s,c]*Wo[d,c]; flat [B,S,C]==[B,T,C,N] view ----
__global__ __launch_bounds__(256) void k_out_small(const float* __restrict__ ctxm,
                                                   const float* __restrict__ Wo,
                                                   float* __restrict__ out) {
    __shared__ float cs[Cc];
    int s = blockIdx.x, b = blockIdx.y;
    int d = threadIdx.x;
    cs[d] = ctxm[((size_t)b * Ss + s) * Cc + d];
    __syncthreads();
    const float* wrow = Wo + (size_t)d * Cc;
    float acc = 0.f;
#pragma unroll 8
    for (int c = 0; c < Cc; ++c)
        acc += cs[c] * wrow[c];
    out[((size_t)b * Ss + s) * Cc + d] = acc;
}

extern "C" void kernel_launch(void* const* d_in, const int* in_sizes, int n_in,
                              void* d_out, int out_size, void* d_ws, size_t ws_size,
                              hipStream_t stream) {
    const float* emb = (const float*)d_in[0];
    const float* Wq  = (const float*)d_in[1];
    const float* Wk  = (const float*)d_in[2];
    const float* Wv  = (const float*)d_in[3];
    const float* Wo  = (const float*)d_in[4];
    float* out = (float*)d_out;

    char* ws = (char*)d_ws;
    size_t off = 0;
    auto alloc = [&](size_t bytes) -> void* {
        void* p = ws + off;
        off = (off + bytes + 255) & ~(size_t)255;
        return p;
    };
    // fp32 scratch, ~31 MiB total
    float* stats = (float*)alloc(16 * 4 * sizeof(float));
    float* x    = (float*)alloc((size_t)Bb * Ss * Cc * 4);   // 6.4 MB
    float* Qb   = (float*)alloc((size_t)Ss * Cc * 4);        // 1.6 MB (per-bh, reused)
    float* Kbb  = (float*)alloc((size_t)Ss * Cc * 4);        // 1.6 MB
    float* Vb   = (float*)alloc((size_t)Ss * Cc * 4);        // 1.6 MB
    float* Sc   = (float*)alloc((size_t)Ss * Ss * 4);        // 9.8 MB (per-bh, reused)
    float* ctxm = (float*)alloc((size_t)Bb * Ss * Cc * 4);   // 6.4 MB head-mean accum

    hipMemsetAsync(stats, 0, 16 * 4 * sizeof(float), stream);
    hipMemsetAsync(ctxm, 0, (size_t)Bb * Ss * Cc * 4, stream);

    k_transpose<<<dim3(7, 8, 32), dim3(32, 8), 0, stream>>>(emb, x);

    for (int bh = 0; bh < 16; ++bh) {
        k_qkv_small<<<dim3(Ss, 3), dim3(256), 0, stream>>>(x, Wq, Wk, Wv, Qb, Kbb, Vb, bh);
        k_scores_small<<<dim3(Ss), dim3(256), 0, stream>>>(Qb, Kbb, Sc, stats, bh);
        k_stats1<<<dim3(1), dim3(64), 0, stream>>>(stats, bh);
        k_pv_small<<<dim3(Ss), dim3(256), 0, stream>>>(Sc, Vb, stats, ctxm, bh);
    }

    k_out_small<<<dim3(Ss, Bb), dim3(256), 0, stream>>>(ctxm, Wo, out);
}

// Round 11
// 262.316 us; speedup vs baseline: 40.3410x; 40.3410x over previous
//
#include <hip/hip_runtime.h>
#include <stdint.h>

typedef unsigned short u16;

#define Bb 4
#define Hh 4
#define Tt 8
#define Cc 256
#define NP 196
#define Ss 1568                 // Tt*NP
#define SCALE_S 0.0252538136f   // 1/sqrt(1568)

typedef __attribute__((ext_vector_type(4))) float floatx4;
typedef __attribute__((ext_vector_type(8))) short shortx8;

__device__ __forceinline__ float bf2f(u16 u) {
    union { unsigned u; float f; } v; v.u = ((unsigned)u) << 16; return v.f;
}
__device__ __forceinline__ u16 f2bf(float f) {
    union { float f; unsigned u; } v; v.f = f;
    unsigned r = v.u + 0x7FFFu + ((v.u >> 16) & 1u);
    return (u16)(r >> 16);
}

// ---- K0: fp32 -> bf16 convert (weights) ----
__global__ __launch_bounds__(256) void k_convw(const float* __restrict__ src, u16* __restrict__ dst, int n) {
    int i = blockIdx.x * 256 + threadIdx.x;
    if (i < n) dst[i] = f2bf(src[i]);
}

// One BK=32 step: 4x4 grid of 16x16x32 bf16 MFMAs per wave (wave covers 64x64).
__device__ __forceinline__ void mfma_step(const u16* As, const u16* Bs, int lane,
                                          int wm, int wn, floatx4 acc[4][4]) {
    const int r15 = lane & 15;
    const int kq  = (lane >> 4) << 3;
    shortx8 a[4], b[4];
#pragma unroll
    for (int i = 0; i < 4; ++i)
        a[i] = *(const shortx8*)(As + (wm * 64 + i * 16 + r15) * 32 + kq);
#pragma unroll
    for (int j = 0; j < 4; ++j)
        b[j] = *(const shortx8*)(Bs + (wn * 64 + j * 16 + r15) * 32 + kq);
#pragma unroll
    for (int i = 0; i < 4; ++i)
#pragma unroll
        for (int j = 0; j < 4; ++j)
            acc[i][j] = __builtin_amdgcn_mfma_f32_16x16x32_bf16(a[i], b[j], acc[i][j], 0, 0, 0);
}

// C[m,n] = sum_k A[m,k]*B[n,k] (both row-major along k), 128x128 tile.
// Register-staged (m92 pattern; correctness-proven vs naive R4<->R5).
__device__ __forceinline__ void gemm_bt_core(const u16* A, const u16* Bm, int lda, int ldb,
                                             int mbase, int mlast, int nbase, int nlast,
                                             int KD, u16* As, u16* Bs, floatx4 acc[4][4]) {
    int tid = threadIdx.x;
    int lane = tid & 63, wave = tid >> 6, wm = wave >> 1, wn = wave & 1;
    int row0 = tid >> 2, row1 = 64 + (tid >> 2);
    int cole = (tid & 3) << 3;                 // 0,8,16,24
    for (int k0 = 0; k0 < KD; k0 += 32) {
        int ga0 = mbase + row0; ga0 = ga0 <= mlast ? ga0 : mlast;
        int ga1 = mbase + row1; ga1 = ga1 <= mlast ? ga1 : mlast;
        int gb0 = nbase + row0; gb0 = gb0 <= nlast ? gb0 : nlast;
        int gb1 = nbase + row1; gb1 = gb1 <= nlast ? gb1 : nlast;
        shortx8 va0 = *(const shortx8*)(A  + (size_t)ga0 * lda + k0 + cole);
        shortx8 va1 = *(const shortx8*)(A  + (size_t)ga1 * lda + k0 + cole);
        shortx8 vb0 = *(const shortx8*)(Bm + (size_t)gb0 * ldb + k0 + cole);
        shortx8 vb1 = *(const shortx8*)(Bm + (size_t)gb1 * ldb + k0 + cole);
        __syncthreads();
        *(shortx8*)(As + row0 * 32 + cole) = va0;
        *(shortx8*)(As + row1 * 32 + cole) = va1;
        *(shortx8*)(Bs + row0 * 32 + cole) = vb0;
        *(shortx8*)(Bs + row1 * 32 + cole) = vb1;
        __syncthreads();
        mfma_step(As, Bs, lane, wm, wn, acc);
    }
}

// ---- K1: emb fp32 [B,T,C,N] -> x bf16 [B,S,C] ----
__global__ void k_transpose(const float* __restrict__ emb, u16* __restrict__ x) {
    __shared__ u16 tile[32][33];
    int bt = blockIdx.z;
    int c0 = blockIdx.y * 32, n0 = blockIdx.x * 32;
    const float* src = emb + (size_t)bt * Cc * NP;
#pragma unroll
    for (int rr = 0; rr < 32; rr += 8) {
        int c = c0 + threadIdx.y + rr;
        int n = n0 + threadIdx.x;
        u16 v = 0;
        if (n < NP) v = f2bf(src[(size_t)c * NP + n]);
        tile[threadIdx.y + rr][threadIdx.x] = v;
    }
    __syncthreads();
    int b = bt / Tt, t = bt % Tt;
    u16* dst = x + ((size_t)b * Ss + (size_t)t * NP) * Cc;
#pragma unroll
    for (int rr = 0; rr < 32; rr += 8) {
        int n = n0 + threadIdx.y + rr;
        int c = c0 + threadIdx.x;
        if (n < NP) dst[(size_t)n * Cc + c] = tile[threadIdx.x][threadIdx.y + rr];
    }
}

// ---- K2: QKV projections, all (qkv,b,h) parallel. V written transposed [C,S]. ----
__global__ __launch_bounds__(256) void k_qkv(const u16* __restrict__ x,
                                             const u16* __restrict__ Wq,
                                             const u16* __restrict__ Wk,
                                             const u16* __restrict__ Wv,
                                             u16* __restrict__ Q, u16* __restrict__ Kb,
                                             u16* __restrict__ Vt) {
    __shared__ __align__(16) u16 As[128 * 32], Bs[128 * 32];
    floatx4 acc[4][4];
#pragma unroll
    for (int i = 0; i < 4; ++i)
#pragma unroll
        for (int j = 0; j < 4; ++j) acc[i][j] = (floatx4)(0.f);
    int z = blockIdx.z;
    int qkv = z >> 4, bh = z & 15, b = bh >> 2, h = bh & 3;
    const u16* A = x + (size_t)b * Ss * Cc;
    const u16* W = (qkv == 0 ? Wq : (qkv == 1 ? Wk : Wv)) + (size_t)h * Cc * Cc;
    int mbase = blockIdx.y * 128, nbase = blockIdx.x * 128;
    gemm_bt_core(A, W, Cc, Cc, mbase, Ss - 1, nbase, Cc - 1, Cc, As, Bs, acc);

    int tid = threadIdx.x, lane = tid & 63, wave = tid >> 6, wm = wave >> 1, wn = wave & 1;
    int rq = (lane >> 4) << 2, cn = lane & 15;
    if (qkv < 2) {
        u16* out = (qkv == 0 ? Q : Kb) + (size_t)bh * Ss * Cc;
#pragma unroll
        for (int i = 0; i < 4; ++i) {
            int mb = mbase + wm * 64 + i * 16 + rq;
#pragma unroll
            for (int j = 0; j < 4; ++j) {
                int n = nbase + wn * 64 + j * 16 + cn;
#pragma unroll
                for (int r = 0; r < 4; ++r) {
                    int m = mb + r;
                    if (m < Ss) out[(size_t)m * Cc + n] = f2bf(acc[i][j][r]);
                }
            }
        }
    } else {
        u16* out = Vt + (size_t)bh * Cc * Ss;
#pragma unroll
        for (int i = 0; i < 4; ++i) {
            int m0 = mbase + wm * 64 + i * 16 + rq;
            if (m0 < Ss) {
#pragma unroll
                for (int j = 0; j < 4; ++j) {
                    int n = nbase + wn * 64 + j * 16 + cn;
                    ushort4 v;
                    v.x = f2bf(acc[i][j][0]); v.y = f2bf(acc[i][j][1]);
                    v.z = f2bf(acc[i][j][2]); v.w = f2bf(acc[i][j][3]);
                    *(ushort4*)(out + (size_t)n * Ss + m0) = v;
                }
            }
        }
    }
}

// ---- K3: Sc = (Q K^T)*SCALE_S -> bf16, + fp32 sum/sumsq atomics per (b,h) ----
__global__ __launch_bounds__(256) void k_scores(const u16* __restrict__ Q,
                                                const u16* __restrict__ Kb,
                                                u16* __restrict__ Sc, float* __restrict__ stats) {
    __shared__ __align__(16) u16 As[128 * 32], Bs[128 * 32];
    __shared__ float sred[8];
    floatx4 acc[4][4];
#pragma unroll
    for (int i = 0; i < 4; ++i)
#pragma unroll
        for (int j = 0; j < 4; ++j) acc[i][j] = (floatx4)(0.f);
    int bh = blockIdx.z;
    const u16* A  = Q  + (size_t)bh * Ss * Cc;
    const u16* Bm = Kb + (size_t)bh * Ss * Cc;
    int mbase = blockIdx.y * 128, nbase = blockIdx.x * 128;
    gemm_bt_core(A, Bm, Cc, Cc, mbase, Ss - 1, nbase, Ss - 1, Cc, As, Bs, acc);

    int tid = threadIdx.x, lane = tid & 63, wave = tid >> 6, wm = wave >> 1, wn = wave & 1;
    int rq = (lane >> 4) << 2, cn = lane & 15;
    u16* out = Sc + (size_t)bh * Ss * Ss;
    float lsum = 0.f, lsq = 0.f;
#pragma unroll
    for (int i = 0; i < 4; ++i) {
        int mb = mbase + wm * 64 + i * 16 + rq;
#pragma unroll
        for (int j = 0; j < 4; ++j) {
            int n = nbase + wn * 64 + j * 16 + cn;
            bool nv = n < Ss;
#pragma unroll
            for (int r = 0; r < 4; ++r) {
                int m = mb + r;
                if (nv && m < Ss) {
                    float v = acc[i][j][r] * SCALE_S;
                    out[(size_t)m * Ss + n] = f2bf(v);
                    lsum += v; lsq += v * v;
                }
            }
        }
    }
#pragma unroll
    for (int mk = 1; mk <= 32; mk <<= 1) { lsum += __shfl_xor(lsum, mk); lsq += __shfl_xor(lsq, mk); }
    if (lane == 0) { sred[wave] = lsum; sred[4 + wave] = lsq; }
    __syncthreads();
    if (tid == 0) atomicAdd(&stats[bh * 4 + 0], sred[0] + sred[1] + sred[2] + sred[3]);
    if (tid == 1) atomicAdd(&stats[bh * 4 + 1], sred[4] + sred[5] + sred[6] + sred[7]);
}

// ---- K4: finalize per-(b,h) mean / inv-std ----
__global__ void k_stats(float* __restrict__ stats) {
    int i = threadIdx.x;
    if (i < 16) {
        float inv  = 1.f / ((float)Ss * (float)Ss);
        float mean = stats[i * 4] * inv;
        float var  = stats[i * 4 + 1] * inv - mean * mean;
        var = fmaxf(var, 0.f);
        stats[i * 4 + 2] = mean;
        stats[i * 4 + 3] = rsqrtf(var + 1e-5f);
    }
}

// ---- K5: ctx = softmax(norm(Sc)) @ V. exp fused into A-staging; rowsum in-block. ----
__global__ __launch_bounds__(256) void k_pv(const u16* __restrict__ Sc,
                                            const u16* __restrict__ Vt,
                                            const float* __restrict__ stats,
                                            u16* __restrict__ ctx) {
    __shared__ __align__(16) u16 As[128 * 32], Bs[128 * 32];
    __shared__ float rs[128];
    floatx4 acc[4][4];
#pragma unroll
    for (int i = 0; i < 4; ++i)
#pragma unroll
        for (int j = 0; j < 4; ++j) acc[i][j] = (floatx4)(0.f);
    int bh = blockIdx.z;
    float mean = stats[bh * 4 + 2], istd = stats[bh * 4 + 3];
    float aa = istd * 1.44269504f;   // log2(e)*istd
    float bb = -mean * aa;
    const u16* A  = Sc + (size_t)bh * Ss * Ss;   // [S][S]
    const u16* Bm = Vt + (size_t)bh * Cc * Ss;   // [C][S]
    int mbase = blockIdx.y * 128, nbase = blockIdx.x * 128;
    int tid = threadIdx.x, lane = tid & 63, wave = tid >> 6, wm = wave >> 1, wn = wave & 1;
    int row0 = tid >> 2, row1 = 64 + (tid >> 2);
    int cole = (tid & 3) << 3;
    float rsum0 = 0.f, rsum1 = 0.f;

    for (int k0 = 0; k0 < Ss; k0 += 32) {
        int ga0 = mbase + row0; ga0 = ga0 <= Ss - 1 ? ga0 : Ss - 1;
        int ga1 = mbase + row1; ga1 = ga1 <= Ss - 1 ? ga1 : Ss - 1;
        shortx8 v0 = *(const shortx8*)(A + (size_t)ga0 * Ss + k0 + cole);
        shortx8 v1 = *(const shortx8*)(A + (size_t)ga1 * Ss + k0 + cole);
        shortx8 vb0 = *(const shortx8*)(Bm + (size_t)(nbase + row0) * Ss + k0 + cole);
        shortx8 vb1 = *(const shortx8*)(Bm + (size_t)(nbase + row1) * Ss + k0 + cole);
        shortx8 o0, o1;
        float p0 = 0.f, p1 = 0.f;
#pragma unroll
        for (int e = 0; e < 8; ++e) {
            float f0 = bf2f((u16)v0[e]);
            float e0 = exp2f(f0 * aa + bb);
            p0 += e0; o0[e] = (short)f2bf(e0);
            float f1 = bf2f((u16)v1[e]);
            float e1 = exp2f(f1 * aa + bb);
            p1 += e1; o1[e] = (short)f2bf(e1);
        }
        rsum0 += p0; rsum1 += p1;
        __syncthreads();
        *(shortx8*)(As + row0 * 32 + cole) = o0;
        *(shortx8*)(As + row1 * 32 + cole) = o1;
        *(shortx8*)(Bs + row0 * 32 + cole) = vb0;
        *(shortx8*)(Bs + row1 * 32 + cole) = vb1;
        __syncthreads();
        mfma_step(As, Bs, lane, wm, wn, acc);
    }
    rsum0 += __shfl_xor(rsum0, 1); rsum0 += __shfl_xor(rsum0, 2);
    rsum1 += __shfl_xor(rsum1, 1); rsum1 += __shfl_xor(rsum1, 2);
    __syncthreads();
    if ((tid & 3) == 0) { rs[tid >> 2] = rsum0; rs[64 + (tid >> 2)] = rsum1; }
    __syncthreads();

    u16* out = ctx + (size_t)bh * Ss * Cc;
    int rq = (lane >> 4) << 2, cn = lane & 15;
#pragma unroll
    for (int i = 0; i < 4; ++i) {
        int ml = wm * 64 + i * 16 + rq;
#pragma unroll
        for (int r = 0; r < 4; ++r) {
            int m = mbase + ml + r;
            if (m < Ss) {
                float invs = 1.f / rs[ml + r];
#pragma unroll
                for (int j = 0; j < 4; ++j) {
                    int n = nbase + wn * 64 + j * 16 + cn;
                    out[(size_t)m * Cc + n] = f2bf(acc[i][j][r] * invs);
                }
            }
        }
    }
}

// ---- K6a: mean over heads: ctx bf16 [B,H,S,C] -> ctxm bf16 [B,S,C] ----
__global__ __launch_bounds__(256) void k_hmean(const u16* __restrict__ ctx, u16* __restrict__ ctxm) {
    int i = blockIdx.x * 256 + threadIdx.x;   // B*S*C/4 exact
    const int PB = Ss * Cc / 4;
    int b = i / PB, g = i % PB;
    float a0 = 0.f, a1 = 0.f, a2 = 0.f, a3 = 0.f;
#pragma unroll
    for (int h = 0; h < Hh; ++h) {
        ushort4 v = *((const ushort4*)(ctx + ((size_t)(b * Hh + h)) * Ss * Cc) + g);
        a0 += bf2f(v.x); a1 += bf2f(v.y); a2 += bf2f(v.z); a3 += bf2f(v.w);
    }
    ushort4 o;
    o.x = f2bf(a0 * 0.25f); o.y = f2bf(a1 * 0.25f);
    o.z = f2bf(a2 * 0.25f); o.w = f2bf(a3 * 0.25f);
    *((ushort4*)(ctxm + (size_t)b * Ss * Cc) + g) = o;
}

// ---- K6b: O = ctxm @ Wo^T -> fp32 d_out (flat [B,S,C] == [B,T,C,N]) ----
__global__ __launch_bounds__(256) void k_out(const u16* __restrict__ ctxm,
                                             const u16* __restrict__ Wo, float* __restrict__ out) {
    __shared__ __align__(16) u16 As[128 * 32], Bs[128 * 32];
    floatx4 acc[4][4];
#pragma unroll
    for (int i = 0; i < 4; ++i)
#pragma unroll
        for (int j = 0; j < 4; ++j) acc[i][j] = (floatx4)(0.f);
    int b = blockIdx.z;
    const u16* A = ctxm + (size_t)b * Ss * Cc;
    int mbase = blockIdx.y * 128, nbase = blockIdx.x * 128;
    gemm_bt_core(A, Wo, Cc, Cc, mbase, Ss - 1, nbase, Cc - 1, Cc, As, Bs, acc);

    int tid = threadIdx.x, lane = tid & 63, wave = tid >> 6, wm = wave >> 1, wn = wave & 1;
    int rq = (lane >> 4) << 2, cn = lane & 15;
    float* o = out + (size_t)b * Ss * Cc;
#pragma unroll
    for (int i = 0; i < 4; ++i) {
        int mb = mbase + wm * 64 + i * 16 + rq;
#pragma unroll
        for (int j = 0; j < 4; ++j) {
            int n = nbase + wn * 64 + j * 16 + cn;
#pragma unroll
            for (int r = 0; r < 4; ++r) {
                int m = mb + r;
                if (m < Ss) o[(size_t)m * Cc + n] = acc[i][j][r];   // fp32 store
            }
        }
    }
}

extern "C" void kernel_launch(void* const* d_in, const int* in_sizes, int n_in,
                              void* d_out, int out_size, void* d_ws, size_t ws_size,
                              hipStream_t stream) {
    const float* emb = (const float*)d_in[0];
    float* out = (float*)d_out;

    char* ws = (char*)d_ws;
    size_t off = 0;
    auto alloc = [&](size_t bytes) -> void* {
        void* p = ws + off;
        off = (off + bytes + 255) & ~(size_t)255;
        return p;
    };
    // Total ~125 MiB. ctx overlays Q (dead after k_scores); ctxm separate (3.2MB).
    float* stats = (float*)alloc(16 * 4 * sizeof(float));
    u16* Wqc  = (u16*)alloc((size_t)Hh * Cc * Cc * 2);
    u16* Wkc  = (u16*)alloc((size_t)Hh * Cc * Cc * 2);
    u16* Wvc  = (u16*)alloc((size_t)Hh * Cc * Cc * 2);
    u16* Woc  = (u16*)alloc((size_t)Cc * Cc * 2);
    u16* x    = (u16*)alloc((size_t)Bb * Ss * Cc * 2);            // 3.2 MB
    u16* Q    = (u16*)alloc((size_t)Bb * Hh * Ss * Cc * 2);       // 12.8 MB (reused as ctx)
    u16* Kb   = (u16*)alloc((size_t)Bb * Hh * Ss * Cc * 2);       // 12.8 MB
    u16* Vt   = (u16*)alloc((size_t)Bb * Hh * Ss * Cc * 2);       // 12.8 MB ([C,S])
    u16* ctxm = (u16*)alloc((size_t)Bb * Ss * Cc * 2);            // 3.2 MB
    u16* Sc   = (u16*)alloc((size_t)Bb * Hh * Ss * Ss * 2);       // 78.7 MB
    u16* ctx  = Q;   // alias

    hipMemsetAsync(stats, 0, 16 * 4 * sizeof(float), stream);

    k_convw<<<dim3(1024), dim3(256), 0, stream>>>((const float*)d_in[1], Wqc, Hh * Cc * Cc);
    k_convw<<<dim3(1024), dim3(256), 0, stream>>>((const float*)d_in[2], Wkc, Hh * Cc * Cc);
    k_convw<<<dim3(1024), dim3(256), 0, stream>>>((const float*)d_in[3], Wvc, Hh * Cc * Cc);
    k_convw<<<dim3(256),  dim3(256), 0, stream>>>((const float*)d_in[4], Woc, Cc * Cc);

    k_transpose<<<dim3(7, 8, 32), dim3(32, 8), 0, stream>>>(emb, x);
    k_qkv<<<dim3(2, 13, 48), dim3(256), 0, stream>>>(x, Wqc, Wkc, Wvc, Q, Kb, Vt);
    k_scores<<<dim3(13, 13, 16), dim3(256), 0, stream>>>(Q, Kb, Sc, stats);
    k_stats<<<dim3(1), dim3(64), 0, stream>>>(stats);
    k_pv<<<dim3(2, 13, 16), dim3(256), 0, stream>>>(Sc, Vt, stats, ctx);
    k_hmean<<<dim3(1568), dim3(256), 0, stream>>>(ctx, ctxm);
    k_out<<<dim3(2, 13, 4), dim3(256), 0, stream>>>(ctxm, Woc, out);
}